// Round 1
// baseline (741.952 us; speedup 1.0000x reference)
//
#include <hip/hip_runtime.h>

#define NUM_FIELDS 39
#define EMB 64
#define NPAIR 741   // C(39,2)

// out[b, pair(p,q), n] = sum_k emb[b,p,k] * emb[b,q,(n-k) & 63]
// Rewritten as: out[n] = sum_m x[(n-m)&63] * y[m]
//   -> lane n holds x_rot[m] = x[(n-m)&63] in registers (preloaded once per p-group)
//   -> y[m] is wave-uniform, read from LDS as float4 broadcasts.
__global__ __launch_bounds__(256) void holo_conv_kernel(
    const float* __restrict__ emb,   // [B, 39, 64]
    float* __restrict__ out)         // [B, 741, 64]
{
    __shared__ __align__(16) float smem[NUM_FIELDS * EMB];  // 9984 B

    const int b    = blockIdx.x;
    const int tid  = threadIdx.x;
    const int lane = tid & 63;
    const int wave = tid >> 6;

    // Stage this batch's embeddings into LDS (coalesced).
    const float* ebase = emb + (size_t)b * (NUM_FIELDS * EMB);
    for (int i = tid; i < NUM_FIELDS * EMB; i += 256) smem[i] = ebase[i];
    __syncthreads();

    float* obase = out + (size_t)b * NPAIR * EMB;

    // Each wave handles p-groups p = wave, wave+4, ...
    for (int p = wave; p < NUM_FIELDS - 1; p += 4) {
        // Preload rotated x into registers: x_rot[m] = x[(lane - m) & 63].
        // For fixed m, lanes read a rotation of 64 consecutive floats
        // -> exactly 2 lanes/bank -> conflict-free.
        float xr[EMB];
        const int xbase = p * EMB;
        #pragma unroll
        for (int m = 0; m < EMB; ++m) xr[m] = smem[xbase + ((lane - m) & 63)];

        const int fbase = 38 * p - (p * (p - 1)) / 2;  // flat pair index of (p, p+1)

        for (int q = p + 1; q < NUM_FIELDS; ++q) {
            const float4* y4 = (const float4*)(smem + q * EMB);  // 16B-aligned, uniform
            float a0 = 0.f, a1 = 0.f, a2 = 0.f, a3 = 0.f;
            #pragma unroll
            for (int mm = 0; mm < EMB / 4; ++mm) {
                const float4 yv = y4[mm];      // uniform ds_read_b128 (broadcast)
                a0 = fmaf(xr[4 * mm + 0], yv.x, a0);
                a1 = fmaf(xr[4 * mm + 1], yv.y, a1);
                a2 = fmaf(xr[4 * mm + 2], yv.z, a2);
                a3 = fmaf(xr[4 * mm + 3], yv.w, a3);
            }
            const size_t oidx = (size_t)(fbase + (q - p - 1)) * EMB + lane;
            obase[oidx] = (a0 + a1) + (a2 + a3);
        }
    }
}

extern "C" void kernel_launch(void* const* d_in, const int* in_sizes, int n_in,
                              void* d_out, int out_size, void* d_ws, size_t ws_size,
                              hipStream_t stream) {
    const float* emb = (const float*)d_in[0];
    // d_in[1]/d_in[2] are field_p/field_q; the combinations(39,2) order is
    // reproduced analytically (flat index = 38p - p(p-1)/2 + (q-p-1)).
    float* out = (float*)d_out;

    const int batch = in_sizes[0] / (NUM_FIELDS * EMB);
    holo_conv_kernel<<<batch, 256, 0, stream>>>(emb, out);
}